// Round 1
// baseline (402.338 us; speedup 1.0000x reference)
//
#include <hip/hip_runtime.h>

#define EPS_F 1e-8f

__device__ __forceinline__ bool pt_in_quad(float px, float py,
                                           const float cx[4], const float cy[4]) {
    float ax = cx[0], ay = cy[0];
    float abx = cx[1] - ax, aby = cy[1] - ay;
    float adx = cx[3] - ax, ady = cy[3] - ay;
    float apx = px - ax, apy = py - ay;
    float pab = apx * abx + apy * aby;
    float pad = apx * adx + apy * ady;
    float nab = abx * abx + aby * aby;
    float nad = adx * adx + ady * ady;
    return (pab > 0.f) && (pab < nab) && (pad > 0.f) && (pad < nad);
}

__global__ void zero_out_kernel(float* out) { out[0] = 0.f; }

__global__ __launch_bounds__(256) void iou3d_loss_kernel(
    const float* __restrict__ pred, const float* __restrict__ target,
    const float* __restrict__ weight, float* __restrict__ out,
    int N, float invN)
{
    int i = blockIdx.x * blockDim.x + threadIdx.x;
    float val = 0.f;
    if (i < N) {
        float b1[7], b2[7];
        #pragma unroll
        for (int k = 0; k < 7; ++k) b1[k] = pred[(long)i * 7 + k];
        #pragma unroll
        for (int k = 0; k < 7; ++k) b2[k] = target[(long)i * 7 + k];
        float wgt = weight[i];

        // ---- box2corners (BOX2D_IDX = [0,1,3,4,6]: x,y,w,h,yaw) ----
        const float txs[4] = {0.5f, -0.5f, -0.5f, 0.5f};
        const float tys[4] = {0.5f,  0.5f, -0.5f, -0.5f};
        float c1x[4], c1y[4], c2x[4], c2y[4];
        {
            float ca = cosf(b1[6]), sa = sinf(b1[6]);
            #pragma unroll
            for (int k = 0; k < 4; ++k) {
                float x4 = txs[k] * b1[3], y4 = tys[k] * b1[4];
                c1x[k] = ca * x4 - sa * y4 + b1[0];
                c1y[k] = sa * x4 + ca * y4 + b1[1];
            }
            ca = cosf(b2[6]); sa = sinf(b2[6]);
            #pragma unroll
            for (int k = 0; k < 4; ++k) {
                float x4 = txs[k] * b2[3], y4 = tys[k] * b2[4];
                c2x[k] = ca * x4 - sa * y4 + b2[0];
                c2y[k] = sa * x4 + ca * y4 + b2[1];
            }
        }

        // ---- collect masked vertices in reference order: c1, c2, ipts ----
        float vx[24], vy[24], ang[24];
        int cnt = 0;
        float sx = 0.f, sy = 0.f;

        #pragma unroll
        for (int k = 0; k < 4; ++k) {
            if (pt_in_quad(c1x[k], c1y[k], c2x, c2y)) {
                vx[cnt] = c1x[k]; vy[cnt] = c1y[k];
                sx += c1x[k]; sy += c1y[k]; ++cnt;
            }
        }
        #pragma unroll
        for (int k = 0; k < 4; ++k) {
            if (pt_in_quad(c2x[k], c2y[k], c1x, c1y)) {
                vx[cnt] = c2x[k]; vy[cnt] = c2y[k];
                sx += c2x[k]; sy += c2y[k]; ++cnt;
            }
        }
        #pragma unroll
        for (int ii = 0; ii < 4; ++ii) {
            float p1x = c1x[ii], p1y = c1y[ii];
            float rx = c1x[(ii + 1) & 3] - p1x, ry = c1y[(ii + 1) & 3] - p1y;
            #pragma unroll
            for (int jj = 0; jj < 4; ++jj) {
                float q1x = c2x[jj], q1y = c2y[jj];
                float ssx = c2x[(jj + 1) & 3] - q1x, ssy = c2y[(jj + 1) & 3] - q1y;
                float denom = rx * ssy - ry * ssx;
                float safe  = (fabsf(denom) < EPS_F) ? 1.f : denom;
                float qpx = q1x - p1x, qpy = q1y - p1y;
                float t = (qpx * ssy - qpy * ssx) / safe;
                float u = (qpx * ry  - qpy * rx ) / safe;
                if ((fabsf(denom) > EPS_F) && (t > 0.f) && (t < 1.f)
                                           && (u > 0.f) && (u < 1.f)) {
                    float px = p1x + t * rx, py = p1y + t * ry;
                    vx[cnt] = px; vy[cnt] = py;
                    sx += px; sy += py; ++cnt;
                }
            }
        }

        // ---- masked_polygon_area: centroid, angles, stable sort, shoelace ----
        float num = (float)(cnt > 1 ? cnt : 1);
        float mx = sx / num, my = sy / num;
        for (int a = 0; a < cnt; ++a) {
            float dx = vx[a] - mx, dy = vy[a] - my;
            vx[a] = dx; vy[a] = dy;
            ang[a] = atan2f(dy, dx);
        }
        // stable insertion sort ascending by angle (ties keep original order,
        // matching jnp.argsort stable + the 1e6+arange unmasked sentinel)
        for (int a = 1; a < cnt; ++a) {
            float ka = ang[a], xx = vx[a], yy = vy[a];
            int b = a - 1;
            while (b >= 0 && ang[b] > ka) {
                ang[b + 1] = ang[b]; vx[b + 1] = vx[b]; vy[b + 1] = vy[b];
                --b;
            }
            ang[b + 1] = ka; vx[b + 1] = xx; vy[b + 1] = yy;
        }
        float cr = 0.f;
        for (int a = 0; a < cnt; ++a) {
            int b = (a + 1 < cnt) ? a + 1 : 0;
            cr += vx[a] * vy[b] - vy[a] * vx[b];
        }
        float area = 0.5f * fabsf(cr);

        // ---- z extent + IoU ----
        float zmax = fminf(b1[2] + 0.5f * b1[5], b2[2] + 0.5f * b2[5]);
        float zmin = fmaxf(b1[2] - 0.5f * b1[5], b2[2] - 0.5f * b2[5]);
        float inter3d = area * fmaxf(zmax - zmin, 0.f);
        float v1 = b1[3] * b1[4] * b1[5];
        float v2 = b2[3] * b2[4] * b2[5];
        float iou = inter3d / (v1 + v2 - inter3d + EPS_F);
        val = (1.f - iou) * wgt * invN;
    }

    // ---- reduction: wave64 shuffle -> LDS -> one atomic per block ----
    #pragma unroll
    for (int off = 32; off > 0; off >>= 1) val += __shfl_down(val, off, 64);
    __shared__ float wsum[4];
    int lane = threadIdx.x & 63, wid = threadIdx.x >> 6;
    if (lane == 0) wsum[wid] = val;
    __syncthreads();
    if (threadIdx.x == 0) {
        float s = wsum[0] + wsum[1] + wsum[2] + wsum[3];
        atomicAdd(out, s);
    }
}

extern "C" void kernel_launch(void* const* d_in, const int* in_sizes, int n_in,
                              void* d_out, int out_size, void* d_ws, size_t ws_size,
                              hipStream_t stream) {
    const float* pred   = (const float*)d_in[0];
    const float* target = (const float*)d_in[1];
    const float* weight = (const float*)d_in[2];
    float* out = (float*)d_out;
    int N = in_sizes[2];  // weight element count

    zero_out_kernel<<<1, 1, 0, stream>>>(out);
    int block = 256;
    int grid = (N + block - 1) / block;
    iou3d_loss_kernel<<<grid, block, 0, stream>>>(pred, target, weight, out,
                                                  N, 1.f / (float)N);
}

// Round 2
// 144.019 us; speedup vs baseline: 2.7936x; 2.7936x over previous
//
#include <hip/hip_runtime.h>

#define EPS_F 1e-8f

// One Sutherland–Hodgman clip stage against a half-plane (side(p) >= 0 is
// inside). Polygon kept entirely in registers: loops fully unrolled, appends
// done as shift-register predicated selects (no dynamic indexing -> no
// scratch). Convex polygon clipped by a half-plane has <= n+1 vertices, so
// OUT_MAX = IN_MAX + 1.
template <int IN_MAX, int OUT_MAX, typename SideF>
__device__ __forceinline__ void clip_stage(float qx[8], float qy[8], int& n,
                                           SideF side) {
    float ox[8], oy[8];
    #pragma unroll
    for (int j = 0; j < OUT_MAX; ++j) { ox[j] = 0.f; oy[j] = 0.f; }

    float d[8];
    #pragma unroll
    for (int k = 0; k < IN_MAX; ++k) d[k] = side(qx[k], qy[k]);

    int m = 0;
    #pragma unroll
    for (int k = 0; k < IN_MAX; ++k) {
        bool act  = (k < n);
        bool wrap = (k + 1 >= n);
        const int kn = (k + 1) % IN_MAX;   // compile-time safe index
        float cxk = qx[k],  cyk = qy[k];
        float nxk = wrap ? qx[0] : qx[kn];
        float nyk = wrap ? qy[0] : qy[kn];
        float dc = d[k];
        float dn = wrap ? d[0] : d[kn];
        bool cin = (dc >= 0.f), nin = (dn >= 0.f);

        // intersection with the clip line (only used when cin != nin,
        // where dc - dn != 0; unused lanes may compute inf/nan harmlessly)
        float t   = dc / (dc - dn);
        float ix_ = cxk + t * (nxk - cxk);
        float iy_ = cyk + t * (nyk - cyk);

        bool a0 = act && cin;            // emit current vertex
        #pragma unroll
        for (int j = 0; j < OUT_MAX; ++j) {
            bool w = a0 && (m == j);
            ox[j] = w ? cxk : ox[j];
            oy[j] = w ? cyk : oy[j];
        }
        m += a0 ? 1 : 0;

        bool a1 = act && (cin != nin);   // emit crossing point
        #pragma unroll
        for (int j = 0; j < OUT_MAX; ++j) {
            bool w = a1 && (m == j);
            ox[j] = w ? ix_ : ox[j];
            oy[j] = w ? iy_ : oy[j];
        }
        m += a1 ? 1 : 0;
    }

    #pragma unroll
    for (int j = 0; j < OUT_MAX; ++j) { qx[j] = ox[j]; qy[j] = oy[j]; }
    n = m;
}

__global__ void zero_out_kernel(float* out) { out[0] = 0.f; }

__global__ __launch_bounds__(256) void iou3d_loss_kernel(
    const float* __restrict__ pred, const float* __restrict__ target,
    const float* __restrict__ weight, float* __restrict__ out,
    int N, float invN)
{
    int i = blockIdx.x * blockDim.x + threadIdx.x;
    float val = 0.f;
    if (i < N) {
        float b1[7], b2[7];
        #pragma unroll
        for (int k = 0; k < 7; ++k) b1[k] = pred[(long)i * 7 + k];
        #pragma unroll
        for (int k = 0; k < 7; ++k) b2[k] = target[(long)i * 7 + k];
        float wgt = weight[i];

        // ---- work in box1's frame: box1 -> axis-aligned [-W,W] x [-H,H] ----
        float s1, c1, s2, c2;
        __sincosf(b1[6], &s1, &c1);
        __sincosf(b2[6], &s2, &c2);
        // relative rotation (a2 - a1) via angle-subtraction identities
        float cd = c1 * c2 + s1 * s2;
        float sd = c1 * s2 - s1 * c2;
        // box2 center in box1's frame: R(-a1) * (t2 - t1)
        float dx = b2[0] - b1[0], dy = b2[1] - b1[1];
        float tx =  c1 * dx + s1 * dy;
        float ty = -s1 * dx + c1 * dy;
        float W = 0.5f * b1[3], H = 0.5f * b1[4];
        float w2 = 0.5f * b2[3], h2 = 0.5f * b2[4];

        // subject polygon: box2 corners in box1 frame, CCW
        float qx[8], qy[8];
        {
            const float txs[4] = {+1.f, -1.f, -1.f, +1.f};
            const float tys[4] = {+1.f, +1.f, -1.f, -1.f};
            #pragma unroll
            for (int k = 0; k < 4; ++k) {
                float lx = txs[k] * w2, ly = tys[k] * h2;
                qx[k] = cd * lx - sd * ly + tx;
                qy[k] = sd * lx + cd * ly + ty;
            }
            #pragma unroll
            for (int k = 4; k < 8; ++k) { qx[k] = 0.f; qy[k] = 0.f; }
        }
        int n = 4;

        // ---- clip against the 4 half-planes of box1's rect ----
        clip_stage<4, 5>(qx, qy, n, [&](float x, float y) { return x + W; });
        clip_stage<5, 6>(qx, qy, n, [&](float x, float y) { return W - x; });
        clip_stage<6, 7>(qx, qy, n, [&](float x, float y) { return y + H; });
        clip_stage<7, 8>(qx, qy, n, [&](float x, float y) { return H - y; });

        // ---- shoelace over the (cyclically ordered) clipped polygon ----
        float cr = 0.f;
        #pragma unroll
        for (int k = 0; k < 8; ++k) {
            bool act  = (k < n);
            bool wrap = (k + 1 >= n);
            const int kn = (k + 1) % 8;
            float nx_ = wrap ? qx[0] : qx[kn];
            float ny_ = wrap ? qy[0] : qy[kn];
            float c = qx[k] * ny_ - qy[k] * nx_;
            cr += act ? c : 0.f;
        }
        float area = 0.5f * fabsf(cr);

        // ---- z extent + IoU ----
        float zmax = fminf(b1[2] + 0.5f * b1[5], b2[2] + 0.5f * b2[5]);
        float zmin = fmaxf(b1[2] - 0.5f * b1[5], b2[2] - 0.5f * b2[5]);
        float inter3d = area * fmaxf(zmax - zmin, 0.f);
        float v1 = b1[3] * b1[4] * b1[5];
        float v2 = b2[3] * b2[4] * b2[5];
        float iou = inter3d / (v1 + v2 - inter3d + EPS_F);
        val = (1.f - iou) * wgt * invN;
    }

    // ---- reduction: wave64 shuffle -> LDS -> one atomic per block ----
    #pragma unroll
    for (int off = 32; off > 0; off >>= 1) val += __shfl_down(val, off, 64);
    __shared__ float wsum[4];
    int lane = threadIdx.x & 63, wid = threadIdx.x >> 6;
    if (lane == 0) wsum[wid] = val;
    __syncthreads();
    if (threadIdx.x == 0) {
        float s = wsum[0] + wsum[1] + wsum[2] + wsum[3];
        atomicAdd(out, s);
    }
}

extern "C" void kernel_launch(void* const* d_in, const int* in_sizes, int n_in,
                              void* d_out, int out_size, void* d_ws, size_t ws_size,
                              hipStream_t stream) {
    const float* pred   = (const float*)d_in[0];
    const float* target = (const float*)d_in[1];
    const float* weight = (const float*)d_in[2];
    float* out = (float*)d_out;
    int N = in_sizes[2];  // weight element count

    zero_out_kernel<<<1, 1, 0, stream>>>(out);
    int block = 256;
    int grid = (N + block - 1) / block;
    iou3d_loss_kernel<<<grid, block, 0, stream>>>(pred, target, weight, out,
                                                  N, 1.f / (float)N);
}

// Round 3
// 136.451 us; speedup vs baseline: 2.9486x; 1.0555x over previous
//
#include <hip/hip_runtime.h>

#define EPS_F 1e-8f

__device__ __forceinline__ float fast_rcp(float x) {
    return __builtin_amdgcn_rcpf(x);  // v_rcp_f32, ~1 ulp
}

__global__ void zero_out_kernel(float* out) { out[0] = 0.f; }

// Area of box2 ∩ box1 via compaction-free Sutherland–Hodgman:
// each stage emits exactly 2 slots per input edge (clipped segment, or a
// doubled point ON the clip line when the edge is fully outside). Extra
// points on the clip line telescope in the shoelace sum, so the area is
// exact. No append counter -> no serial dependency chain, full ILP.
__global__ __launch_bounds__(256) void iou3d_loss_kernel(
    const float* __restrict__ pred, const float* __restrict__ target,
    const float* __restrict__ weight, float* __restrict__ out,
    int N, float invN)
{
    int i = blockIdx.x * blockDim.x + threadIdx.x;
    float val = 0.f;
    if (i < N) {
        float b1[7], b2[7];
        #pragma unroll
        for (int k = 0; k < 7; ++k) b1[k] = pred[(long)i * 7 + k];
        #pragma unroll
        for (int k = 0; k < 7; ++k) b2[k] = target[(long)i * 7 + k];
        float wgt = weight[i];

        // ---- box1's frame: box1 = axis-aligned [-W,W] x [-H,H] ----
        float s1, c1, s2, c2;
        __sincosf(b1[6], &s1, &c1);
        __sincosf(b2[6], &s2, &c2);
        float cd = c1 * c2 + s1 * s2;          // cos(a2-a1)
        float sd = c1 * s2 - s1 * c2;          // sin(a2-a1)
        float dxc = b2[0] - b1[0], dyc = b2[1] - b1[1];
        float tx =  c1 * dxc + s1 * dyc;
        float ty = -s1 * dxc + c1 * dyc;
        float W = 0.5f * b1[3], H = 0.5f * b1[4];
        float w2 = 0.5f * b2[3], h2 = 0.5f * b2[4];

        // box2 corners in box1 frame (CCW)
        float p0x[4], p0y[4];
        {
            const float txs[4] = {+1.f, -1.f, -1.f, +1.f};
            const float tys[4] = {+1.f, +1.f, -1.f, -1.f};
            #pragma unroll
            for (int k = 0; k < 4; ++k) {
                float lx = txs[k] * w2, ly = tys[k] * h2;
                p0x[k] = cd * lx - sd * ly + tx;
                p0y[k] = sd * lx + cd * ly + ty;
            }
        }

        // ---- Stage A: clip x >= -W  (4 edges -> 8 slots) ----
        float p1x[8], p1y[8];
        {
            float d[4]; bool in_[4];
            #pragma unroll
            for (int k = 0; k < 4; ++k) { d[k] = p0x[k] + W; in_[k] = d[k] >= 0.f; }
            #pragma unroll
            for (int k = 0; k < 4; ++k) {
                const int kn = (k + 1) & 3;
                float t  = d[k] * fast_rcp(d[k] - d[kn]);
                float yI = p0y[k] + t * (p0y[kn] - p0y[k]);
                float Qy = (in_[k] != in_[kn]) ? yI : p0y[k];
                p1x[2*k]   = in_[k]  ? p0x[k]  : -W;
                p1y[2*k]   = in_[k]  ? p0y[k]  : Qy;
                p1x[2*k+1] = in_[kn] ? p0x[kn] : -W;
                p1y[2*k+1] = in_[kn] ? p0y[kn] : Qy;
            }
        }

        // ---- Stage B: clip x <= W  (8 edges -> 16 slots) ----
        float p2x[16], p2y[16];
        {
            float d[8]; bool in_[8];
            #pragma unroll
            for (int k = 0; k < 8; ++k) { d[k] = W - p1x[k]; in_[k] = d[k] >= 0.f; }
            #pragma unroll
            for (int k = 0; k < 8; ++k) {
                const int kn = (k + 1) & 7;
                float t  = d[k] * fast_rcp(d[k] - d[kn]);
                float yI = p1y[k] + t * (p1y[kn] - p1y[k]);
                float Qy = (in_[k] != in_[kn]) ? yI : p1y[k];
                p2x[2*k]   = in_[k]  ? p1x[k]  : W;
                p2y[2*k]   = in_[k]  ? p1y[k]  : Qy;
                p2x[2*k+1] = in_[kn] ? p1x[kn] : W;
                p2y[2*k+1] = in_[kn] ? p1y[kn] : Qy;
            }
        }

        // ---- Stage C (y >= -H) streamed into Stage D (y <= H) + shoelace ----
        float d3[16]; bool i3[16];
        #pragma unroll
        for (int k = 0; k < 16; ++k) { d3[k] = p2y[k] + H; i3[k] = d3[k] >= 0.f; }

        float cr = 0.f;
        float s0x = 0.f, s0y = 0.f;            // stream point 0 (for wrap)
        float sPx = 0.f, sPy = 0.f, dP = 0.f;  // prev stream point + its D-side
        bool  inP = false;
        float fAx = 0.f, fAy = 0.f;            // first D-emitted alpha
        float pBx = 0.f, pBy = 0.f;            // last  D-emitted beta

        auto processD = [&](float sx, float sy, float dS, bool inS, bool first) {
            float tD  = dP * fast_rcp(dP - dS);
            float xID = sPx + tD * (sx - sPx);
            float QxD = (inP != inS) ? xID : sPx;
            float Ax = inP ? sPx : QxD;
            float Ay = inP ? sPy : H;
            float Bx = inS ? sx  : QxD;
            float By = inS ? sy  : H;
            if (first) { fAx = Ax; fAy = Ay; }
            else       { cr += pBx * Ay - pBy * Ax; }
            cr += Ax * By - Ay * Bx;
            pBx = Bx; pBy = By;
            sPx = sx; sPy = sy; dP = dS; inP = inS;
        };

        #pragma unroll
        for (int k = 0; k < 16; ++k) {
            const int kn = (k + 1) & 15;
            float t  = d3[k] * fast_rcp(d3[k] - d3[kn]);
            float xI = p2x[k] + t * (p2x[kn] - p2x[k]);
            float Qx = (i3[k] != i3[kn]) ? xI : p2x[k];
            float ax = i3[k]  ? p2x[k]  : Qx;
            float ay = i3[k]  ? p2y[k]  : -H;
            float bx = i3[kn] ? p2x[kn] : Qx;
            float by = i3[kn] ? p2y[kn] : -H;

            // stream the two points into stage D
            {
                float dS = H - ay; bool inS = dS >= 0.f;
                if (k == 0) { s0x = ax; s0y = ay; sPx = ax; sPy = ay; dP = dS; inP = inS; }
                else        processD(ax, ay, dS, inS, false);
            }
            {
                float dS = H - by; bool inS = dS >= 0.f;
                processD(bx, by, dS, inS, (k == 0));
            }
        }
        // wrap stream edge (s31 -> s0), then close the D-cycle
        {
            float dS = H - s0y; bool inS = dS >= 0.f;
            processD(s0x, s0y, dS, inS, false);
        }
        cr += pBx * fAy - pBy * fAx;

        float area = 0.5f * fabsf(cr);

        // ---- z extent + IoU ----
        float zmax = fminf(b1[2] + 0.5f * b1[5], b2[2] + 0.5f * b2[5]);
        float zmin = fmaxf(b1[2] - 0.5f * b1[5], b2[2] - 0.5f * b2[5]);
        float inter3d = area * fmaxf(zmax - zmin, 0.f);
        float v1 = b1[3] * b1[4] * b1[5];
        float v2 = b2[3] * b2[4] * b2[5];
        float iou = inter3d / (v1 + v2 - inter3d + EPS_F);
        val = (1.f - iou) * wgt * invN;
    }

    // ---- reduction: wave64 shuffle -> LDS -> one atomic per block ----
    #pragma unroll
    for (int off = 32; off > 0; off >>= 1) val += __shfl_down(val, off, 64);
    __shared__ float wsum[4];
    int lane = threadIdx.x & 63, wid = threadIdx.x >> 6;
    if (lane == 0) wsum[wid] = val;
    __syncthreads();
    if (threadIdx.x == 0) {
        float s = wsum[0] + wsum[1] + wsum[2] + wsum[3];
        atomicAdd(out, s);
    }
}

extern "C" void kernel_launch(void* const* d_in, const int* in_sizes, int n_in,
                              void* d_out, int out_size, void* d_ws, size_t ws_size,
                              hipStream_t stream) {
    const float* pred   = (const float*)d_in[0];
    const float* target = (const float*)d_in[1];
    const float* weight = (const float*)d_in[2];
    float* out = (float*)d_out;
    int N = in_sizes[2];  // weight element count

    zero_out_kernel<<<1, 1, 0, stream>>>(out);
    int block = 256;
    int grid = (N + block - 1) / block;
    iou3d_loss_kernel<<<grid, block, 0, stream>>>(pred, target, weight, out,
                                                  N, 1.f / (float)N);
}

// Round 4
// 113.975 us; speedup vs baseline: 3.5300x; 1.1972x over previous
//
#include <hip/hip_runtime.h>

#define EPS_F 1e-8f

__device__ __forceinline__ float fast_rcp(float x) {
    return __builtin_amdgcn_rcpf(x);  // v_rcp_f32, ~1 ulp
}

__global__ void zero_out_kernel(float* out) { out[0] = 0.f; }

// Contribution of one directed edge (a->b) of a CCW polygon to
// -2 * Area(P ∩ [-W,W]x[-H,H])  ... summed over edges, Area = -0.5 * sum.
// Method: A = -∮ h(y) dx with h(y)=clamp(y,-H,H)+H, edge clipped to the
// x-slab (vertical closure segments have dx=0 -> contribute 0). The clipped
// t-interval is split at the y=±H crossings; trapezoid rule per piece is
// exact (h piecewise-linear). Branch-free, NaN-free (guarded denominators),
// every edge independent -> full ILP.
__device__ __forceinline__ float edge_contrib(float ax, float ay,
                                              float bx, float by,
                                              float W, float H) {
    float dx = bx - ax, dy = by - ay;
    float sdx = (fabsf(dx) < 1e-20f) ? 1e-20f : dx;
    float sdy = (fabsf(dy) < 1e-20f) ? 1e-20f : dy;
    float rdx = fast_rcp(sdx);
    float rdy = fast_rcp(sdy);

    // clip t-range to x in [-W, W]
    float tA = (-W - ax) * rdx;
    float tB = ( W - ax) * rdx;
    float ta = fmaxf(fminf(tA, tB), 0.f);
    float tb = fminf(fmaxf(tA, tB), 1.f);
    tb = fmaxf(ta, tb);                 // empty range -> ta == tb

    // split points where y crosses -H / +H
    float u0 = (-H - ay) * rdy;
    float u1 = ( H - ay) * rdy;
    float tm0 = fminf(u0, u1), tm1 = fmaxf(u0, u1);
    float t1 = fminf(fmaxf(tm0, ta), tb);
    float t2 = fminf(fmaxf(tm1, ta), tb);

    // evaluate x, h at the 4 breakpoints
    float x0 = fmaf(ta, dx, ax), y0 = fmaf(ta, dy, ay);
    float x1 = fmaf(t1, dx, ax), y1 = fmaf(t1, dy, ay);
    float x2 = fmaf(t2, dx, ax), y2 = fmaf(t2, dy, ay);
    float x3 = fmaf(tb, dx, ax), y3 = fmaf(tb, dy, ay);
    float h0 = fminf(fmaxf(y0, -H), H) + H;
    float h1 = fminf(fmaxf(y1, -H), H) + H;
    float h2 = fminf(fmaxf(y2, -H), H) + H;
    float h3 = fminf(fmaxf(y3, -H), H) + H;

    // 2 * ∫ h dx along the clipped edge (trapezoid per piece, exact)
    return (x1 - x0) * (h0 + h1) + (x2 - x1) * (h1 + h2) + (x3 - x2) * (h2 + h3);
}

#define EPT 2  // elements per thread

__global__ __launch_bounds__(256) void iou3d_loss_kernel(
    const float* __restrict__ pred, const float* __restrict__ target,
    const float* __restrict__ weight, float* __restrict__ out,
    int N, float invN)
{
    int base = blockIdx.x * (256 * EPT) + threadIdx.x;
    float val = 0.f;

    #pragma unroll
    for (int e = 0; e < EPT; ++e) {
        int i = base + e * 256;
        if (i >= N) continue;

        float b1[7], b2[7];
        #pragma unroll
        for (int k = 0; k < 7; ++k) b1[k] = pred[(long)i * 7 + k];
        #pragma unroll
        for (int k = 0; k < 7; ++k) b2[k] = target[(long)i * 7 + k];
        float wgt = weight[i];

        // ---- box1's frame: box1 = axis-aligned [-W,W] x [-H,H] ----
        float s1, c1, s2, c2;
        __sincosf(b1[6], &s1, &c1);
        __sincosf(b2[6], &s2, &c2);
        float cd = c1 * c2 + s1 * s2;          // cos(a2-a1)
        float sd = c1 * s2 - s1 * c2;          // sin(a2-a1)
        float dxc = b2[0] - b1[0], dyc = b2[1] - b1[1];
        float tx =  c1 * dxc + s1 * dyc;
        float ty = -s1 * dxc + c1 * dyc;
        float W = 0.5f * b1[3], H = 0.5f * b1[4];
        float w2 = 0.5f * b2[3], h2 = 0.5f * b2[4];

        // box2 corners in box1 frame (CCW)
        float q0x = cd * ( w2) - sd * ( h2) + tx, q0y = sd * ( w2) + cd * ( h2) + ty;
        float q1x = cd * (-w2) - sd * ( h2) + tx, q1y = sd * (-w2) + cd * ( h2) + ty;
        float q2x = cd * (-w2) - sd * (-h2) + tx, q2y = sd * (-w2) + cd * (-h2) + ty;
        float q3x = cd * ( w2) - sd * (-h2) + tx, q3y = sd * ( w2) + cd * (-h2) + ty;

        // 4 independent edge integrals
        float s  = edge_contrib(q0x, q0y, q1x, q1y, W, H)
                 + edge_contrib(q1x, q1y, q2x, q2y, W, H)
                 + edge_contrib(q2x, q2y, q3x, q3y, W, H)
                 + edge_contrib(q3x, q3y, q0x, q0y, W, H);
        float area = 0.5f * fabsf(s);

        // ---- z extent + IoU ----
        float zmax = fminf(b1[2] + 0.5f * b1[5], b2[2] + 0.5f * b2[5]);
        float zmin = fmaxf(b1[2] - 0.5f * b1[5], b2[2] - 0.5f * b2[5]);
        float inter3d = area * fmaxf(zmax - zmin, 0.f);
        float v1 = b1[3] * b1[4] * b1[5];
        float v2 = b2[3] * b2[4] * b2[5];
        float iou = inter3d / (v1 + v2 - inter3d + EPS_F);
        val += (1.f - iou) * wgt * invN;
    }

    // ---- reduction: wave64 shuffle -> LDS -> one atomic per block ----
    #pragma unroll
    for (int off = 32; off > 0; off >>= 1) val += __shfl_down(val, off, 64);
    __shared__ float wsum[4];
    int lane = threadIdx.x & 63, wid = threadIdx.x >> 6;
    if (lane == 0) wsum[wid] = val;
    __syncthreads();
    if (threadIdx.x == 0) {
        float ssum = wsum[0] + wsum[1] + wsum[2] + wsum[3];
        atomicAdd(out, ssum);
    }
}

extern "C" void kernel_launch(void* const* d_in, const int* in_sizes, int n_in,
                              void* d_out, int out_size, void* d_ws, size_t ws_size,
                              hipStream_t stream) {
    const float* pred   = (const float*)d_in[0];
    const float* target = (const float*)d_in[1];
    const float* weight = (const float*)d_in[2];
    float* out = (float*)d_out;
    int N = in_sizes[2];  // weight element count

    zero_out_kernel<<<1, 1, 0, stream>>>(out);
    int block = 256;
    int grid = (N + block * EPT - 1) / (block * EPT);
    iou3d_loss_kernel<<<grid, block, 0, stream>>>(pred, target, weight, out,
                                                  N, 1.f / (float)N);
}

// Round 5
// 101.149 us; speedup vs baseline: 3.9777x; 1.1268x over previous
//
#include <hip/hip_runtime.h>

#define EPS_F 1e-8f
#define EPT 4  // elements per thread; grid 1024 -> 4 waves/SIMD, 4 chains each

__device__ __forceinline__ float fast_rcp(float x) {
    return __builtin_amdgcn_rcpf(x);  // v_rcp_f32, ~1 ulp
}

__global__ void zero_out_kernel(float* out) { out[0] = 0.f; }

// Contribution of one directed edge (a->b) of a CCW polygon to
// 2*signed-Area(P ∩ [-W,W]x[-H,H]) via the boundary integral of
// h(y)=clamp(y,-H,H)+H over the edge clipped to the x-slab (vertical
// closure segments have dx=0 -> contribute 0). Split at y=±H crossings;
// trapezoid per piece is exact (h piecewise-linear). Branch-free, NaN-free.
__device__ __forceinline__ float edge_contrib(float ax, float ay,
                                              float bx, float by,
                                              float W, float H) {
    float dx = bx - ax, dy = by - ay;
    float sdx = (fabsf(dx) < 1e-20f) ? 1e-20f : dx;
    float sdy = (fabsf(dy) < 1e-20f) ? 1e-20f : dy;
    float rdx = fast_rcp(sdx);
    float rdy = fast_rcp(sdy);

    float tA = (-W - ax) * rdx;
    float tB = ( W - ax) * rdx;
    float ta = fmaxf(fminf(tA, tB), 0.f);
    float tb = fminf(fmaxf(tA, tB), 1.f);
    tb = fmaxf(ta, tb);

    float u0 = (-H - ay) * rdy;
    float u1 = ( H - ay) * rdy;
    float tm0 = fminf(u0, u1), tm1 = fmaxf(u0, u1);
    float t1 = fminf(fmaxf(tm0, ta), tb);
    float t2 = fminf(fmaxf(tm1, ta), tb);

    float x0 = fmaf(ta, dx, ax), y0 = fmaf(ta, dy, ay);
    float x1 = fmaf(t1, dx, ax), y1 = fmaf(t1, dy, ay);
    float x2 = fmaf(t2, dx, ax), y2 = fmaf(t2, dy, ay);
    float x3 = fmaf(tb, dx, ax), y3 = fmaf(tb, dy, ay);
    float h0 = fminf(fmaxf(y0, -H), H) + H;
    float h1 = fminf(fmaxf(y1, -H), H) + H;
    float h2 = fminf(fmaxf(y2, -H), H) + H;
    float h3 = fminf(fmaxf(y3, -H), H) + H;

    return (x1 - x0) * (h0 + h1) + (x2 - x1) * (h1 + h2) + (x3 - x2) * (h2 + h3);
}

__global__ __launch_bounds__(256, 4) void iou3d_loss_kernel(
    const float* __restrict__ pred, const float* __restrict__ target,
    const float* __restrict__ weight, float* __restrict__ out,
    int N, float invN)
{
    int base = blockIdx.x * (256 * EPT) + threadIdx.x;

    // ---- phase 1: hoist ALL loads (independent; one vmcnt drain) ----
    float b1[EPT][7], b2[EPT][7], wgt[EPT];
    #pragma unroll
    for (int e = 0; e < EPT; ++e) {
        int i = base + e * 256;
        int j = (i < N) ? i : 0;              // safe index; wgt=0 kills OOB
        #pragma unroll
        for (int k = 0; k < 7; ++k) b1[e][k] = pred[(long)j * 7 + k];
        #pragma unroll
        for (int k = 0; k < 7; ++k) b2[e][k] = target[(long)j * 7 + k];
        wgt[e] = (i < N) ? weight[j] : 0.f;
    }

    // ---- phase 2: EPT independent compute chains ----
    float val = 0.f;
    #pragma unroll
    for (int e = 0; e < EPT; ++e) {
        float s1, c1, s2, c2;
        __sincosf(b1[e][6], &s1, &c1);
        __sincosf(b2[e][6], &s2, &c2);
        float cd = c1 * c2 + s1 * s2;          // cos(a2-a1)
        float sd = c1 * s2 - s1 * c2;          // sin(a2-a1)
        float dxc = b2[e][0] - b1[e][0], dyc = b2[e][1] - b1[e][1];
        float tx =  c1 * dxc + s1 * dyc;
        float ty = -s1 * dxc + c1 * dyc;
        float W = 0.5f * b1[e][3], H = 0.5f * b1[e][4];
        float w2 = 0.5f * b2[e][3], h2 = 0.5f * b2[e][4];

        // box2 corners in box1 frame (CCW)
        float q0x = cd * ( w2) - sd * ( h2) + tx, q0y = sd * ( w2) + cd * ( h2) + ty;
        float q1x = cd * (-w2) - sd * ( h2) + tx, q1y = sd * (-w2) + cd * ( h2) + ty;
        float q2x = cd * (-w2) - sd * (-h2) + tx, q2y = sd * (-w2) + cd * (-h2) + ty;
        float q3x = cd * ( w2) - sd * (-h2) + tx, q3y = sd * ( w2) + cd * (-h2) + ty;

        float s  = edge_contrib(q0x, q0y, q1x, q1y, W, H)
                 + edge_contrib(q1x, q1y, q2x, q2y, W, H)
                 + edge_contrib(q2x, q2y, q3x, q3y, W, H)
                 + edge_contrib(q3x, q3y, q0x, q0y, W, H);
        float area = 0.5f * fabsf(s);

        float zmax = fminf(b1[e][2] + 0.5f * b1[e][5], b2[e][2] + 0.5f * b2[e][5]);
        float zmin = fmaxf(b1[e][2] - 0.5f * b1[e][5], b2[e][2] - 0.5f * b2[e][5]);
        float inter3d = area * fmaxf(zmax - zmin, 0.f);
        float v1 = b1[e][3] * b1[e][4] * b1[e][5];
        float v2 = b2[e][3] * b2[e][4] * b2[e][5];
        float iou = inter3d * fast_rcp(v1 + v2 - inter3d + EPS_F);
        val += (1.f - iou) * wgt[e] * invN;
    }

    // ---- reduction: wave64 shuffle -> LDS -> one atomic per block ----
    #pragma unroll
    for (int off = 32; off > 0; off >>= 1) val += __shfl_down(val, off, 64);
    __shared__ float wsum[4];
    int lane = threadIdx.x & 63, wid = threadIdx.x >> 6;
    if (lane == 0) wsum[wid] = val;
    __syncthreads();
    if (threadIdx.x == 0) {
        float ssum = wsum[0] + wsum[1] + wsum[2] + wsum[3];
        atomicAdd(out, ssum);
    }
}

extern "C" void kernel_launch(void* const* d_in, const int* in_sizes, int n_in,
                              void* d_out, int out_size, void* d_ws, size_t ws_size,
                              hipStream_t stream) {
    const float* pred   = (const float*)d_in[0];
    const float* target = (const float*)d_in[1];
    const float* weight = (const float*)d_in[2];
    float* out = (float*)d_out;
    int N = in_sizes[2];  // weight element count

    zero_out_kernel<<<1, 1, 0, stream>>>(out);
    int block = 256;
    int grid = (N + block * EPT - 1) / (block * EPT);
    iou3d_loss_kernel<<<grid, block, 0, stream>>>(pred, target, weight, out,
                                                  N, 1.f / (float)N);
}